// Round 8
// baseline (112.981 us; speedup 1.0000x reference)
//
#include <hip/hip_runtime.h>
#include <math.h>

#define CN 128
#define SN 56
#define PCOLS 33                  // P plane cols (px = row*33 + col), 12 rows
#define PXS 404                   // plane stride, ushorts (mult of 4 -> b64-aligned)
#define SDW 202                   // plane stride, dwords (202 % 32 = 10 -> spread banks)
#define DYS (6 * PXS + PCOLS)     // 2457: gather dy step (ushorts)
#define DXS (PXS + 1)             // 405:  gather dx step
#define LOG2E 1.44269504088896341f

typedef float  fr4 __attribute__((ext_vector_type(4)));
typedef short  sh8 __attribute__((ext_vector_type(8)));

__device__ __forceinline__ unsigned short f2bf(float f) {
    unsigned u = __float_as_uint(f);
    u += 0x7FFFu + ((u >> 16) & 1u);          // RNE
    return (unsigned short)(u >> 16);
}
// pack two f32 -> bf16x2 (round half up): low = f0, high = f1
__device__ __forceinline__ int pk2(float f0, float f1) {
    unsigned u0 = __float_as_uint(f0) + 0x8000u;
    unsigned u1 = __float_as_uint(f1) + 0x8000u;
    return (int)__builtin_amdgcn_perm(u1, u0, 0x07060302u);
}
__device__ __forceinline__ float bf2f(unsigned short s) {
    return __uint_as_float(((unsigned)s) << 16);
}

// ---- Kernel A: Gaussian bank pre-swizzled into B-fragment order ----
// bank[c][ks][nt][lane][8 ushorts]: element j = G^T[tap = nt*16+(lane&15)]
// [u = ks*32+(lane>>4)*8+j] in bf16; tap >= 36 -> 0.
__global__ void bank_kernel(const float* __restrict__ theta,
                            const float* __restrict__ p,
                            const float* __restrict__ sig,
                            const float* __restrict__ a,
                            unsigned short* __restrict__ bank) {
    int t = blockIdx.x * 256 + threadIdx.x;       // < 128*4*3*64 = 98304
    int lane = t & 63;
    int grp  = t >> 6;
    int nt = grp % 3;
    int ks = (grp / 3) & 3;
    int c  = grp / 12;
    int tap = nt * 16 + (lane & 15);
    int ub  = ks * 32 + (lane >> 4) * 8;
    sh8 v = {0,0,0,0,0,0,0,0};
    if (tap < 36) {
        int ky = tap / 6, kx = tap - ky * 6;
        float xv = -3.0f + 1.2f * ky;
        float yv = -3.0f + 1.2f * kx;
        #pragma unroll
        for (int j = 0; j < 8; ++j) {
            int pr = c * CN + ub + j;
            float th = theta[pr], pv = p[pr], sv = sig[pr], av = a[pr];
            float ct = __cosf(th), st = __sinf(th);
            float xr =  xv * ct + yv * st;
            float yr = -xv * st + yv * ct;
            float e  = -0.5f * (xr * xr / (pv * pv) + yr * yr / (sv * sv));
            float g  = (av / (2.0f * 3.14159265358979323846f * pv * sv))
                       * __builtin_amdgcn_exp2f(e * LOG2E);
            v[j] = (short)f2bf(g);
        }
    }
    ((sh8*)bank)[t] = v;
}

// ---- Main kernel: one block per (b, c, h, w); 512 threads = 8 waves ----
// Four 7-row phases; P[36 taps][12x33 px] bf16 in LDS (29.1 KB -> 4 blocks/CU,
// whole 1024-block grid co-resident). Phase k>0 reuses the previous phase's
// last 5 P rows via an in-plane shift copy (GEMM: 25 tiles phase 0, 15 after).
__global__ __launch_bounds__(512, 4) void divnorm_mfma(
        const float* __restrict__ x, const unsigned short* __restrict__ bank,
        const float* __restrict__ nI, const float* __restrict__ nU,
        const float* __restrict__ bias, float* __restrict__ out)
{
    __shared__ alignas(16) unsigned short SH[36 * PXS];   // 29088 B
    int* SD = (int*)SH;

    const int bid = blockIdx.x;
    const int w   = bid & 1;
    const int h   = (bid >> 1) & 1;
    const int c   = (bid >> 2) & 127;
    const int b   = bid >> 9;
    const int tid = threadIdx.x;
    const int lane = tid & 63;
    const int wv   = tid >> 6;          // 0..7
    const int l15  = lane & 15;
    const int lg   = lane >> 4;

    // B-frags: 12 coalesced 16B loads from the pre-swizzled bank.
    sh8 Bf[3][4];
    {
        const sh8* bp = (const sh8*)bank + (size_t)c * 768 + lane;
        #pragma unroll
        for (int ks = 0; ks < 4; ++ks)
            #pragma unroll
            for (int nt = 0; nt < 3; ++nt)
                Bf[nt][ks] = bp[(ks * 3 + nt) * 64];
    }

    // Per-lane nI (A multipliers): u = ks*32 + lg*8 + j.
    float nIr[4][8];
    {
        const float* nc = nI + c * CN;
        #pragma unroll
        for (int ks = 0; ks < 4; ++ks) {
            const float4* q = (const float4*)(nc + ks * 32 + lg * 8);
            float4 q0 = q[0], q1 = q[1];
            nIr[ks][0] = q0.x; nIr[ks][1] = q0.y; nIr[ks][2] = q0.z; nIr[ks][3] = q0.w;
            nIr[ks][4] = q1.x; nIr[ks][5] = q1.y; nIr[ks][6] = q1.z; nIr[ks][7] = q1.w;
        }
    }

    const float* xc = x   + (size_t)(b * CN + c) * (SN * SN);
    float*       oc = out + (size_t)(b * CN + c) * (SN * SN);
    const float nUc = nU[c];
    const float bn  = __builtin_amdgcn_exp2f(nUc * __builtin_amdgcn_logf(bias[c]));
    const int   c0   = 28 * w;
    const int   c0m2 = c0 - 2;

    // Scatter plane bases (dwords) for this lane's 3 taps (8B-aligned: SDW even).
    const int pof0 = l15 * SDW;
    const int pof1 = (16 + l15) * SDW;
    const int pof2 = (32 + l15) * SDW;

    #pragma unroll 1
    for (int ph = 0; ph < 4; ++ph) {
        const int r0   = 28 * h + 7 * ph;
        const int r0m2 = r0 - 2;
        const int tb   = ph ? 10 : 0;        // first M-tile this phase

        // ---- Halo share: shift P rows 7..11 -> rows 0..4 (165 ush/plane) ----
        if (ph > 0) {
            for (int idx = tid; idx < 36 * 165; idx += 512) {
                int pl  = idx / 165;
                int off = idx - pl * 165;
                SH[pl * PXS + off] = SH[pl * PXS + 231 + off];
            }
            __syncthreads();
        }

        // ---- GEMM + transposed scatter (tile = tb + wv + 8i, tiles tb..24) ----
        int pidx = (tb + wv) * 16 + l15;
        int prl  = pidx / PCOLS;
        int pcl  = pidx - prl * PCOLS;
        int prow = r0m2 + prl;
        int pcol = c0m2 + pcl;
        bool val = ((unsigned)prow < 56u) && ((unsigned)pcol < 56u);
        float xv = xc[val ? (prow * SN + pcol) : 0];

        #pragma unroll 1
        for (int tile = tb + wv; tile < 25; tile += 8) {
            float L = val ? __builtin_amdgcn_logf(xv) : -1e30f;   // OOB -> t=0

            // Prefetch next tile's x (dummy-clamped on last iteration).
            {
                int np   = pidx + 128;
                int nprl = np / PCOLS;
                int npcl = np - nprl * PCOLS;
                int nprw = r0m2 + nprl;
                int npcc = c0m2 + npcl;
                val = ((unsigned)nprw < 56u) && ((unsigned)npcc < 56u);
                xv  = xc[val ? (nprw * SN + npcc) : 0];
                pidx = np;
            }

            fr4 a0 = {0.f,0.f,0.f,0.f}, a1 = {0.f,0.f,0.f,0.f}, a2 = {0.f,0.f,0.f,0.f};
            #pragma unroll
            for (int ks = 0; ks < 4; ++ks) {
                float t[8];
                #pragma unroll
                for (int j = 0; j < 8; ++j)
                    t[j] = __builtin_amdgcn_exp2f(nIr[ks][j] * L);
                int4 ai;
                ai.x = pk2(t[0], t[1]); ai.y = pk2(t[2], t[3]);
                ai.z = pk2(t[4], t[5]); ai.w = pk2(t[6], t[7]);
                sh8 af = *(sh8*)&ai;
                a0 = __builtin_amdgcn_mfma_f32_16x16x32_bf16(af, Bf[0][ks], a0, 0, 0, 0);
                a1 = __builtin_amdgcn_mfma_f32_16x16x32_bf16(af, Bf[1][ks], a1, 0, 0, 0);
                a2 = __builtin_amdgcn_mfma_f32_16x16x32_bf16(af, Bf[2][ks], a2, 0, 0, 0);
            }

            // C (px = tile*16+lg*4+r, tap = nt*16+l15) -> P[tap][px], b64 stores.
            int pbd = tile * 8 + lg * 2;                  // dword px base (even)
            int2 v0, v1;
            v0.x = pk2(a0[0], a0[1]); v0.y = pk2(a0[2], a0[3]);
            v1.x = pk2(a1[0], a1[1]); v1.y = pk2(a1[2], a1[3]);
            *(int2*)&SD[pof0 + pbd] = v0;
            *(int2*)&SD[pof1 + pbd] = v1;
            if (l15 < 4) {                                // taps 32..35 only
                int2 v2;
                v2.x = pk2(a2[0], a2[1]); v2.y = pk2(a2[2], a2[3]);
                *(int2*)&SD[pof2 + pbd] = v2;
            }
        }
        __syncthreads();

        // ---- Gather: out = x^nU / (bias^nU + sum_tap P[tap][px(tap)]) ----
        if (tid < 7 * 28) {
            int oy = tid / 28;
            int ox = tid - oy * 28;
            const unsigned short* pb = &SH[oy * PCOLS + ox];
            float s = 0.0f;
            #pragma unroll
            for (int dy = 0; dy < 6; ++dy)
                #pragma unroll
                for (int dx = 0; dx < 6; ++dx)
                    s += bf2f(pb[dy * DYS + dx * DXS]);
            int y  = r0 + oy;
            int xg = c0 + ox;
            float xq  = xc[y * SN + xg];
            float num = __builtin_amdgcn_exp2f(nUc * __builtin_amdgcn_logf(xq));
            oc[y * SN + xg] = num / (bn + s);
        }
        if (ph < 3) __syncthreads();      // gather reads done before next shift
    }
}

extern "C" void kernel_launch(void* const* d_in, const int* in_sizes, int n_in,
                              void* d_out, int out_size, void* d_ws, size_t ws_size,
                              hipStream_t stream) {
    const float* x     = (const float*)d_in[0];
    const float* theta = (const float*)d_in[1];
    const float* p     = (const float*)d_in[2];
    const float* sig   = (const float*)d_in[3];
    const float* a     = (const float*)d_in[4];
    const float* nI    = (const float*)d_in[5];
    const float* nU    = (const float*)d_in[6];
    const float* bias  = (const float*)d_in[7];
    float* out = (float*)d_out;
    unsigned short* bank = (unsigned short*)d_ws;   // 128*768*8 ushorts = 1.57 MB

    hipLaunchKernelGGL(bank_kernel, dim3(384), dim3(256), 0, stream,
                       theta, p, sig, a, bank);
    hipLaunchKernelGGL(divnorm_mfma, dim3(2 * CN * 4), dim3(512), 0, stream,
                       x, bank, nI, nU, bias, out);
}

// Round 10
// 101.753 us; speedup vs baseline: 1.1103x; 1.1103x over previous
//
#include <hip/hip_runtime.h>
#include <math.h>

#define CN 128
#define SN 56
#define PCOLS 33                  // P plane: 19 rows x 33 cols (px = row*33+col)
#define PXS 660                   // plane stride, ushorts (mult of 4)
#define SDW 330                   // plane stride, dwords (330 % 32 = 10 -> spread banks)
#define DYS (6 * PXS + PCOLS)     // 3993: gather dy step (ushorts)
#define DXS (PXS + 1)             // 661:  gather dx step
#define LOG2E 1.44269504088896341f

typedef float    fr4 __attribute__((ext_vector_type(4)));
typedef _Float16 hf8 __attribute__((ext_vector_type(8)));   // MFMA operand type
typedef __fp16   pkv __attribute__((ext_vector_type(2)));   // cvt_pkrtz result type

__device__ __forceinline__ int h2i(pkv h) {
    union { pkv h; int i; } u; u.h = h; return u.i;
}

// ---- Kernel A: Gaussian bank pre-swizzled into B-fragment order (f16) ----
// bank[c][ks][nt][lane][8 halfs]: element j = G^T[tap = nt*16+(lane&15)]
// [u = ks*32+(lane>>4)*8+j]; tap >= 36 -> 0.
__global__ void bank_kernel(const float* __restrict__ theta,
                            const float* __restrict__ p,
                            const float* __restrict__ sig,
                            const float* __restrict__ a,
                            unsigned short* __restrict__ bank) {
    int t = blockIdx.x * 256 + threadIdx.x;       // < 128*4*3*64 = 98304
    int lane = t & 63;
    int grp  = t >> 6;
    int nt = grp % 3;
    int ks = (grp / 3) & 3;
    int c  = grp / 12;
    int tap = nt * 16 + (lane & 15);
    int ub  = ks * 32 + (lane >> 4) * 8;
    hf8 v = {0,0,0,0,0,0,0,0};
    if (tap < 36) {
        int ky = tap / 6, kx = tap - ky * 6;
        float xv = -3.0f + 1.2f * ky;
        float yv = -3.0f + 1.2f * kx;
        #pragma unroll
        for (int j = 0; j < 8; ++j) {
            int pr = c * CN + ub + j;
            float th = theta[pr], pv = p[pr], sv = sig[pr], av = a[pr];
            float ct = __cosf(th), st = __sinf(th);
            float xr =  xv * ct + yv * st;
            float yr = -xv * st + yv * ct;
            float e  = -0.5f * (xr * xr / (pv * pv) + yr * yr / (sv * sv));
            float g  = (av / (2.0f * 3.14159265358979323846f * pv * sv))
                       * __builtin_amdgcn_exp2f(e * LOG2E);
            v[j] = (_Float16)g;
        }
    }
    ((hf8*)bank)[t] = v;
}

// ---- Main kernel: one block per (b, c, h, w); 512 threads = 8 waves ----
// Two 14-row bands; P[36 taps][19x33 px] f16 in LDS. Band 1 reuses band 0's
// 5 overlapping halo rows via an in-plane shift copy (30 GEMM tiles vs 40).
// A-frags generated in-register: t = exp2(nI * log2 x), packed with
// v_cvt_pkrtz_f16_f32; GEMM = mfma_f32_16x16x32_f16; 36-tap gather -> out.
__global__ __launch_bounds__(512, 4) void divnorm_mfma(
        const float* __restrict__ x, const unsigned short* __restrict__ bank,
        const float* __restrict__ nI, const float* __restrict__ nU,
        const float* __restrict__ bias, float* __restrict__ out)
{
    __shared__ alignas(16) unsigned short SH[36 * PXS];   // 47520 B
    int* SD = (int*)SH;

    const int bid = blockIdx.x;
    const int w   = bid & 1;
    const int h   = (bid >> 1) & 1;
    const int c   = (bid >> 2) & 127;
    const int b   = bid >> 9;
    const int tid = threadIdx.x;
    const int lane = tid & 63;
    const int wv   = tid >> 6;          // 0..7
    const int l15  = lane & 15;
    const int lg   = lane >> 4;

    // B-frags: 12 coalesced 16B loads from the pre-swizzled bank.
    hf8 Bf[3][4];
    {
        const hf8* bp = (const hf8*)bank + (size_t)c * 768 + lane;
        #pragma unroll
        for (int ks = 0; ks < 4; ++ks)
            #pragma unroll
            for (int nt = 0; nt < 3; ++nt)
                Bf[nt][ks] = bp[(ks * 3 + nt) * 64];
    }

    // Per-lane nI (A multipliers): u = ks*32 + lg*8 + j.
    float nIr[4][8];
    {
        const float* nc = nI + c * CN;
        #pragma unroll
        for (int ks = 0; ks < 4; ++ks) {
            const float4* q = (const float4*)(nc + ks * 32 + lg * 8);
            float4 q0 = q[0], q1 = q[1];
            nIr[ks][0] = q0.x; nIr[ks][1] = q0.y; nIr[ks][2] = q0.z; nIr[ks][3] = q0.w;
            nIr[ks][4] = q1.x; nIr[ks][5] = q1.y; nIr[ks][6] = q1.z; nIr[ks][7] = q1.w;
        }
    }

    const float* xc = x   + (size_t)(b * CN + c) * (SN * SN);
    float*       oc = out + (size_t)(b * CN + c) * (SN * SN);
    const float nUc = nU[c];
    const float bn  = __builtin_amdgcn_exp2f(nUc * __builtin_amdgcn_logf(bias[c]));
    const int   c0m2 = 28 * w - 2;

    // Scatter plane bases (dwords) for this lane's 3 taps (b64-aligned: SDW even).
    const int pof0 = l15 * SDW;
    const int pof1 = (16 + l15) * SDW;
    const int pof2 = (32 + l15) * SDW;

    #pragma unroll 1
    for (int phase = 0; phase < 2; ++phase) {
        const int r0   = 28 * h + 14 * phase;
        const int r0m2 = r0 - 2;
        const int tb   = phase ? 10 : 0;                    // first M-tile
        const int nit  = phase ? ((wv < 6) ? 4 : 3) : 5;    // tiles this wave

        // ---- GEMM + transposed scatter (tile = tb + wv + 8i) ----
        int pidx = (tb + wv) * 16 + l15;
        int prl  = pidx / PCOLS;
        int pcl  = pidx - prl * PCOLS;
        int prow = r0m2 + prl;
        int pcol = c0m2 + pcl;
        bool val = ((unsigned)prow < 56u) && ((unsigned)pcol < 56u);
        float xv = xc[val ? (prow * SN + pcol) : 0];

        #pragma unroll 1
        for (int i = 0; i < nit; ++i) {
            float L = val ? __builtin_amdgcn_logf(xv) : -1e30f;   // OOB -> t=0

            // Prefetch next M-tile's x (last iter loads a harmless dummy).
            {
                int np   = pidx + 128;
                int nprl = np / PCOLS;
                int npcl = np - nprl * PCOLS;
                int nprw = r0m2 + nprl;
                int npcc = c0m2 + npcl;
                val = ((unsigned)nprw < 56u) && ((unsigned)npcc < 56u);
                xv  = xc[val ? (nprw * SN + npcc) : 0];
                pidx = np;
            }

            fr4 a0 = {0.f,0.f,0.f,0.f}, a1 = {0.f,0.f,0.f,0.f}, a2 = {0.f,0.f,0.f,0.f};
            #pragma unroll
            for (int ks = 0; ks < 4; ++ks) {
                float t[8];
                #pragma unroll
                for (int j = 0; j < 8; ++j)
                    t[j] = __builtin_amdgcn_exp2f(nIr[ks][j] * L);
                union { pkv h[4]; hf8 v; } af;
                af.h[0] = __builtin_amdgcn_cvt_pkrtz(t[0], t[1]);
                af.h[1] = __builtin_amdgcn_cvt_pkrtz(t[2], t[3]);
                af.h[2] = __builtin_amdgcn_cvt_pkrtz(t[4], t[5]);
                af.h[3] = __builtin_amdgcn_cvt_pkrtz(t[6], t[7]);
                a0 = __builtin_amdgcn_mfma_f32_16x16x32_f16(af.v, Bf[0][ks], a0, 0, 0, 0);
                a1 = __builtin_amdgcn_mfma_f32_16x16x32_f16(af.v, Bf[1][ks], a1, 0, 0, 0);
                a2 = __builtin_amdgcn_mfma_f32_16x16x32_f16(af.v, Bf[2][ks], a2, 0, 0, 0);
            }

            // C (px = tile*16+lg*4+r, tap = nt*16+l15) -> P[tap][px], b64 stores.
            int pbd = (tb + wv + 8 * i) * 8 + lg * 2;     // dword px base (even)
            int2 v0, v1;
            v0.x = h2i(__builtin_amdgcn_cvt_pkrtz(a0[0], a0[1]));
            v0.y = h2i(__builtin_amdgcn_cvt_pkrtz(a0[2], a0[3]));
            v1.x = h2i(__builtin_amdgcn_cvt_pkrtz(a1[0], a1[1]));
            v1.y = h2i(__builtin_amdgcn_cvt_pkrtz(a1[2], a1[3]));
            *(int2*)&SD[pof0 + pbd] = v0;
            *(int2*)&SD[pof1 + pbd] = v1;
            if (l15 < 4) {                                 // taps 32..35 only
                int2 v2;
                v2.x = h2i(__builtin_amdgcn_cvt_pkrtz(a2[0], a2[1]));
                v2.y = h2i(__builtin_amdgcn_cvt_pkrtz(a2[2], a2[3]));
                *(int2*)&SD[pof2 + pbd] = v2;
            }
        }
        __syncthreads();

        // ---- Gather: out = x^nU / (bias^nU + sum_tap P[tap][px(tap)]) ----
        if (tid < 14 * 28) {
            int oy = tid / 28;
            int ox = tid - oy * 28;
            const unsigned short* pb = &SH[oy * PCOLS + ox];
            float s = 0.0f;
            #pragma unroll
            for (int dy = 0; dy < 6; ++dy)
                #pragma unroll
                for (int dx = 0; dx < 6; ++dx)
                    s += (float)(*(const _Float16*)&pb[dy * DYS + dx * DXS]);
            int y  = r0 + oy;
            int xg = c0m2 + 2 + ox;
            float xq  = xc[y * SN + xg];
            float num = __builtin_amdgcn_exp2f(nUc * __builtin_amdgcn_logf(xq));
            oc[y * SN + xg] = num / (bn + s);
        }
        __syncthreads();

        // ---- Halo share: band-0 P rows 14..18 -> band-1 rows 0..4 ----
        if (phase == 0) {
            // px 0..159 (80 dw) per plane; src = dst + 462 ush (231 dw).
            for (int idx = tid; idx < 36 * 80; idx += 512) {
                int pl  = idx / 80;
                int off = idx - pl * 80;
                SD[pl * SDW + off] = SD[pl * SDW + 231 + off];
            }
            __syncthreads();
        }
    }
}

extern "C" void kernel_launch(void* const* d_in, const int* in_sizes, int n_in,
                              void* d_out, int out_size, void* d_ws, size_t ws_size,
                              hipStream_t stream) {
    const float* x     = (const float*)d_in[0];
    const float* theta = (const float*)d_in[1];
    const float* p     = (const float*)d_in[2];
    const float* sig   = (const float*)d_in[3];
    const float* a     = (const float*)d_in[4];
    const float* nI    = (const float*)d_in[5];
    const float* nU    = (const float*)d_in[6];
    const float* bias  = (const float*)d_in[7];
    float* out = (float*)d_out;
    unsigned short* bank = (unsigned short*)d_ws;   // 128*768*8 halfs = 1.57 MB

    hipLaunchKernelGGL(bank_kernel, dim3(384), dim3(256), 0, stream,
                       theta, p, sig, a, bank);
    hipLaunchKernelGGL(divnorm_mfma, dim3(2 * CN * 4), dim3(512), 0, stream,
                       x, bank, nI, nU, bias, out);
}

// Round 12
// 97.987 us; speedup vs baseline: 1.1530x; 1.0384x over previous
//
#include <hip/hip_runtime.h>
#include <math.h>

#define CN 128
#define SN 56
#define PXS 772                   // plane stride, ushorts (386 dw, %32 = 2)
#define SDW 386                   // plane stride, dwords
#define DYS 4696                  // gather dy step, ushorts = 6*PXS + 64
#define DXS 773                   // gather dx step, ushorts = PXS + 1
#define LOG2E 1.44269504088896341f

typedef float    fr4 __attribute__((ext_vector_type(4)));
typedef _Float16 hf8 __attribute__((ext_vector_type(8)));   // MFMA operand type
typedef __fp16   pkv __attribute__((ext_vector_type(2)));   // cvt_pkrtz result type

__device__ __forceinline__ int h2i(pkv h) {
    union { pkv h; int i; } u; u.h = h; return u.i;
}

// ---- Kernel A: Gaussian bank pre-swizzled into B-fragment order (f16) ----
// bank[c][ks][nt][lane][8 halfs]: element j = G^T[tap = nt*16+(lane&15)]
// [u = ks*32+(lane>>4)*8+j]; tap >= 36 -> 0.
__global__ void bank_kernel(const float* __restrict__ theta,
                            const float* __restrict__ p,
                            const float* __restrict__ sig,
                            const float* __restrict__ a,
                            unsigned short* __restrict__ bank) {
    int t = blockIdx.x * 256 + threadIdx.x;       // < 128*4*3*64 = 98304
    int lane = t & 63;
    int grp  = t >> 6;
    int nt = grp % 3;
    int ks = (grp / 3) & 3;
    int c  = grp / 12;
    int tap = nt * 16 + (lane & 15);
    int ub  = ks * 32 + (lane >> 4) * 8;
    hf8 v = {0,0,0,0,0,0,0,0};
    if (tap < 36) {
        int ky = tap / 6, kx = tap - ky * 6;
        float xv = -3.0f + 1.2f * ky;
        float yv = -3.0f + 1.2f * kx;
        #pragma unroll
        for (int j = 0; j < 8; ++j) {
            int pr = c * CN + ub + j;
            float th = theta[pr], pv = p[pr], sv = sig[pr], av = a[pr];
            float ct = __cosf(th), st = __sinf(th);
            float xr =  xv * ct + yv * st;
            float yr = -xv * st + yv * ct;
            float e  = -0.5f * (xr * xr / (pv * pv) + yr * yr / (sv * sv));
            float g  = (av / (2.0f * 3.14159265358979323846f * pv * sv))
                       * __builtin_amdgcn_exp2f(e * LOG2E);
            v[j] = (_Float16)g;
        }
    }
    ((hf8*)bank)[t] = v;
}

// ---- Main kernel: one block per (b, c, row-half h); 512 threads = 8 waves.
// Grid 512 = exactly 2 blocks/CU (55.6 KB LDS), zero dispatch tail.
// Four 7-row phases over the full 56-col width; P[36 taps][12 x 64 px] f16.
// Phase p>0 reuses the previous phase's last 5 P rows (in-plane shift copy);
// GEMM: 48 tiles phase 0, 28 after. A-frags in-register (t = exp2(nI*log2 x),
// v_cvt_pkrtz pack); mfma_f32_16x16x32_f16; 36-tap immediate-offset gather.
__global__ __launch_bounds__(512, 4) void divnorm_mfma(
        const float* __restrict__ x, const unsigned short* __restrict__ bank,
        const float* __restrict__ nI, const float* __restrict__ nU,
        const float* __restrict__ bias, float* __restrict__ out)
{
    __shared__ alignas(16) unsigned short SH[36 * PXS];   // 55584 B
    int*  SD  = (int*)SH;
    int2* SD2 = (int2*)SH;

    const int bid = blockIdx.x;
    const int h   = bid & 1;
    const int c   = (bid >> 1) & 127;
    const int b   = bid >> 8;
    const int tid = threadIdx.x;
    const int lane = tid & 63;
    const int wv   = tid >> 6;          // 0..7
    const int l15  = lane & 15;
    const int lg   = lane >> 4;

    // B-frags: 12 coalesced 16B loads from the pre-swizzled bank.
    hf8 Bf[3][4];
    {
        const hf8* bp = (const hf8*)bank + (size_t)c * 768 + lane;
        #pragma unroll
        for (int ks = 0; ks < 4; ++ks)
            #pragma unroll
            for (int nt = 0; nt < 3; ++nt)
                Bf[nt][ks] = bp[(ks * 3 + nt) * 64];
    }

    // Per-lane nI (A multipliers): u = ks*32 + lg*8 + j.
    float nIr[4][8];
    {
        const float* nc = nI + c * CN;
        #pragma unroll
        for (int ks = 0; ks < 4; ++ks) {
            const float4* q = (const float4*)(nc + ks * 32 + lg * 8);
            float4 q0 = q[0], q1 = q[1];
            nIr[ks][0] = q0.x; nIr[ks][1] = q0.y; nIr[ks][2] = q0.z; nIr[ks][3] = q0.w;
            nIr[ks][4] = q1.x; nIr[ks][5] = q1.y; nIr[ks][6] = q1.z; nIr[ks][7] = q1.w;
        }
    }

    const float* xc = x   + (size_t)(b * CN + c) * (SN * SN);
    float*       oc = out + (size_t)(b * CN + c) * (SN * SN);
    const float nUc = nU[c];
    const float bn  = __builtin_amdgcn_exp2f(nUc * __builtin_amdgcn_logf(bias[c]));

    // Scatter plane bases (dwords) for this lane's 3 taps (b64-aligned: SDW even).
    const int pof0 = l15 * SDW;
    const int pof1 = (16 + l15) * SDW;
    const int pof2 = (32 + l15) * SDW;

    // Gather geometry (once): 392 outputs, 1 per thread.
    const int oy = tid / 56;
    const int ox = tid - oy * 56;

    #pragma unroll 1
    for (int ph = 0; ph < 4; ++ph) {
        const int r0   = 28 * h + 7 * ph;
        const int r0m2 = r0 - 2;
        const int tb   = ph ? 20 : 0;        // first M-tile this phase

        // ---- Halo share: shift P rows 7..11 -> rows 0..4 (80 int2/plane) ----
        if (ph > 0) {
            __syncthreads();                 // prior gather reads done
            for (int idx = tid; idx < 36 * 80; idx += 512) {
                int pl  = idx / 80;
                int off = idx - pl * 80;
                SD2[pl * 193 + off] = SD2[pl * 193 + 112 + off];
            }
            __syncthreads();
        }

        // ---- GEMM + transposed scatter (tile = tb + wv + 8i, tiles tb..47) ----
        int pidx = (tb + wv) * 16 + l15;     // px index; row = px>>6, col = px&63
        int prow = r0m2 + (pidx >> 6);
        int pcol = (pidx & 63) - 2;
        bool val = ((unsigned)prow < 56u) && ((unsigned)pcol < 56u);
        float xv = xc[val ? (prow * SN + pcol) : 0];

        #pragma unroll 1
        for (int tile = tb + wv; tile < 48; tile += 8) {
            float L = val ? __builtin_amdgcn_logf(xv) : -1e30f;   // OOB -> t=0

            // Prefetch next tile's x (dummy-clamped on last iteration).
            {
                int np   = pidx + 128;
                int nprw = r0m2 + (np >> 6);
                int npcc = (np & 63) - 2;
                val = ((unsigned)nprw < 56u) && ((unsigned)npcc < 56u);
                xv  = xc[val ? (nprw * SN + npcc) : 0];
                pidx = np;
            }

            fr4 a0 = {0.f,0.f,0.f,0.f}, a1 = {0.f,0.f,0.f,0.f}, a2 = {0.f,0.f,0.f,0.f};
            #pragma unroll
            for (int ks = 0; ks < 4; ++ks) {
                float t[8];
                #pragma unroll
                for (int j = 0; j < 8; ++j)
                    t[j] = __builtin_amdgcn_exp2f(nIr[ks][j] * L);
                union { pkv h[4]; hf8 v; } af;
                af.h[0] = __builtin_amdgcn_cvt_pkrtz(t[0], t[1]);
                af.h[1] = __builtin_amdgcn_cvt_pkrtz(t[2], t[3]);
                af.h[2] = __builtin_amdgcn_cvt_pkrtz(t[4], t[5]);
                af.h[3] = __builtin_amdgcn_cvt_pkrtz(t[6], t[7]);
                a0 = __builtin_amdgcn_mfma_f32_16x16x32_f16(af.v, Bf[0][ks], a0, 0, 0, 0);
                a1 = __builtin_amdgcn_mfma_f32_16x16x32_f16(af.v, Bf[1][ks], a1, 0, 0, 0);
                a2 = __builtin_amdgcn_mfma_f32_16x16x32_f16(af.v, Bf[2][ks], a2, 0, 0, 0);
            }

            // C (px = tile*16+lg*4+r, tap = nt*16+l15) -> P[tap][px], b64 stores.
            int pbd = tile * 8 + lg * 2;                  // dword px base (even)
            int2 v0, v1;
            v0.x = h2i(__builtin_amdgcn_cvt_pkrtz(a0[0], a0[1]));
            v0.y = h2i(__builtin_amdgcn_cvt_pkrtz(a0[2], a0[3]));
            v1.x = h2i(__builtin_amdgcn_cvt_pkrtz(a1[0], a1[1]));
            v1.y = h2i(__builtin_amdgcn_cvt_pkrtz(a1[2], a1[3]));
            *(int2*)&SD[pof0 + pbd] = v0;
            *(int2*)&SD[pof1 + pbd] = v1;
            if (l15 < 4) {                                // taps 32..35 only
                int2 v2;
                v2.x = h2i(__builtin_amdgcn_cvt_pkrtz(a2[0], a2[1]));
                v2.y = h2i(__builtin_amdgcn_cvt_pkrtz(a2[2], a2[3]));
                *(int2*)&SD[pof2 + pbd] = v2;
            }
        }
        __syncthreads();

        // ---- Gather: out = x^nU / (bias^nU + sum_tap P[tap][px(tap)]) ----
        if (tid < 7 * 56) {
            const unsigned short* pb = &SH[oy * 64 + ox];
            float s = 0.0f;
            #pragma unroll
            for (int dy = 0; dy < 6; ++dy)
                #pragma unroll
                for (int dx = 0; dx < 6; ++dx)
                    s += (float)(*(const _Float16*)&pb[dy * DYS + dx * DXS]);
            int y = r0 + oy;
            float xq  = xc[y * SN + ox];
            float num = __builtin_amdgcn_exp2f(nUc * __builtin_amdgcn_logf(xq));
            oc[y * SN + ox] = num / (bn + s);
        }
    }
}

extern "C" void kernel_launch(void* const* d_in, const int* in_sizes, int n_in,
                              void* d_out, int out_size, void* d_ws, size_t ws_size,
                              hipStream_t stream) {
    const float* x     = (const float*)d_in[0];
    const float* theta = (const float*)d_in[1];
    const float* p     = (const float*)d_in[2];
    const float* sig   = (const float*)d_in[3];
    const float* a     = (const float*)d_in[4];
    const float* nI    = (const float*)d_in[5];
    const float* nU    = (const float*)d_in[6];
    const float* bias  = (const float*)d_in[7];
    float* out = (float*)d_out;
    unsigned short* bank = (unsigned short*)d_ws;   // 128*768*8 halfs = 1.57 MB

    hipLaunchKernelGGL(bank_kernel, dim3(384), dim3(256), 0, stream,
                       theta, p, sig, a, bank);
    // (b, c, h) -> 2*128*2 = 512 blocks (r11 bug: launched 256, dropping b=1)
    hipLaunchKernelGGL(divnorm_mfma, dim3(4 * CN), dim3(512), 0, stream,
                       x, bank, nI, nU, bias, out);
}